// Round 1
// baseline (145.009 us; speedup 1.0000x reference)
//
#include <hip/hip_runtime.h>

#define T_LEN 16384
#define VAR_EPS 1e-5f

// One block per row. 256 threads, float4 loads -> 16 iters/thread.
__global__ __launch_bounds__(256) void pearson_row_kernel(
    const float* __restrict__ pred, const float* __restrict__ target,
    float* __restrict__ row_loss)
{
    const int row = blockIdx.x;
    const int tid = threadIdx.x;
    const float4* __restrict__ p4 =
        (const float4*)(pred + (size_t)row * T_LEN);
    const float4* __restrict__ t4 =
        (const float4*)(target + (size_t)row * T_LEN);

    float sp = 0.f, st = 0.f, spp = 0.f, stt = 0.f, spt = 0.f;

    #pragma unroll 4
    for (int i = tid; i < T_LEN / 4; i += 256) {
        float4 a = p4[i];
        float4 b = t4[i];
        sp  += a.x + a.y + a.z + a.w;
        st  += b.x + b.y + b.z + b.w;
        spp += a.x * a.x + a.y * a.y + a.z * a.z + a.w * a.w;
        stt += b.x * b.x + b.y * b.y + b.z * b.z + b.w * b.w;
        spt += a.x * b.x + a.y * b.y + a.z * b.z + a.w * b.w;
    }

    // Wave (64-lane) shuffle reduction.
    #pragma unroll
    for (int off = 32; off > 0; off >>= 1) {
        sp  += __shfl_down(sp,  off);
        st  += __shfl_down(st,  off);
        spp += __shfl_down(spp, off);
        stt += __shfl_down(stt, off);
        spt += __shfl_down(spt, off);
    }

    __shared__ float ws[4][5];
    const int lane = tid & 63;
    const int wave = tid >> 6;
    if (lane == 0) {
        ws[wave][0] = sp;  ws[wave][1] = st;  ws[wave][2] = spp;
        ws[wave][3] = stt; ws[wave][4] = spt;
    }
    __syncthreads();

    if (tid == 0) {
        float S_p  = ws[0][0] + ws[1][0] + ws[2][0] + ws[3][0];
        float S_t  = ws[0][1] + ws[1][1] + ws[2][1] + ws[3][1];
        float S_pp = ws[0][2] + ws[1][2] + ws[2][2] + ws[3][2];
        float S_tt = ws[0][3] + ws[1][3] + ws[2][3] + ws[3][3];
        float S_pt = ws[0][4] + ws[1][4] + ws[2][4] + ws[3][4];

        const float T   = (float)T_LEN;
        const float inv = 1.0f / T;
        float cp2 = S_pp - S_p * S_p * inv;   // sum of squared centered pred
        float ct2 = S_tt - S_t * S_t * inv;
        float num = S_pt - S_p * S_t * inv;

        float var_p = cp2 / (T - 1.0f);
        float var_t = ct2 / (T - 1.0f);
        float denom = sqrtf(cp2 * ct2);
        float safe  = (denom > 0.0f) ? denom : 1.0f;
        float corr  = num / safe;
        bool valid = (var_p > VAR_EPS) && (var_t > VAR_EPS) &&
                     (denom > 0.0f) && !isnan(corr);
        row_loss[row] = valid ? (1.0f - corr) : 1.0f;
    }
}

// Single-block reduction of B row losses -> mean.
__global__ __launch_bounds__(256) void reduce_mean_kernel(
    const float* __restrict__ row_loss, float* __restrict__ out, int B)
{
    const int tid = threadIdx.x;
    float s = 0.f;
    for (int i = tid; i < B; i += 256) s += row_loss[i];

    #pragma unroll
    for (int off = 32; off > 0; off >>= 1) s += __shfl_down(s, off);

    __shared__ float ws[4];
    if ((tid & 63) == 0) ws[tid >> 6] = s;
    __syncthreads();
    if (tid == 0)
        out[0] = (ws[0] + ws[1] + ws[2] + ws[3]) / (float)B;
}

extern "C" void kernel_launch(void* const* d_in, const int* in_sizes, int n_in,
                              void* d_out, int out_size, void* d_ws, size_t ws_size,
                              hipStream_t stream) {
    const float* pred   = (const float*)d_in[0];
    const float* target = (const float*)d_in[1];
    float* out = (float*)d_out;
    float* row_loss = (float*)d_ws;   // B floats of scratch

    const int B = in_sizes[0] / T_LEN;

    pearson_row_kernel<<<B, 256, 0, stream>>>(pred, target, row_loss);
    reduce_mean_kernel<<<1, 256, 0, stream>>>(row_loss, out, B);
}

// Round 2
// 144.916 us; speedup vs baseline: 1.0006x; 1.0006x over previous
//
#include <hip/hip_runtime.h>

#define T_LEN 16384
#define VAR_EPS 1e-5f

// One block per row. 512 threads (8 waves -> 32 waves/CU at 1024 blocks),
// fully unrolled 8 float4 iters/thread issued in two 8-load batches.
__global__ __launch_bounds__(512) void pearson_row_kernel(
    const float* __restrict__ pred, const float* __restrict__ target,
    float* __restrict__ out, float inv_B)
{
    const int row = blockIdx.x;
    const int tid = threadIdx.x;
    const float4* __restrict__ p4 =
        (const float4*)(pred + (size_t)row * T_LEN);
    const float4* __restrict__ t4 =
        (const float4*)(target + (size_t)row * T_LEN);

    float sp = 0.f, st = 0.f, spp = 0.f, stt = 0.f, spt = 0.f;

    // T/4 = 4096 float4 per row; 512 threads -> 8 per thread; 2 batches of 4.
    #pragma unroll
    for (int half = 0; half < 2; ++half) {
        const int i0 = tid + half * 2048;
        // Issue all 8 loads before any use (8 outstanding vmcnt).
        float4 a0 = p4[i0];
        float4 a1 = p4[i0 + 512];
        float4 a2 = p4[i0 + 1024];
        float4 a3 = p4[i0 + 1536];
        float4 b0 = t4[i0];
        float4 b1 = t4[i0 + 512];
        float4 b2 = t4[i0 + 1024];
        float4 b3 = t4[i0 + 1536];

        sp  += (a0.x + a0.y + a0.z + a0.w) + (a1.x + a1.y + a1.z + a1.w)
             + (a2.x + a2.y + a2.z + a2.w) + (a3.x + a3.y + a3.z + a3.w);
        st  += (b0.x + b0.y + b0.z + b0.w) + (b1.x + b1.y + b1.z + b1.w)
             + (b2.x + b2.y + b2.z + b2.w) + (b3.x + b3.y + b3.z + b3.w);
        spp += a0.x*a0.x + a0.y*a0.y + a0.z*a0.z + a0.w*a0.w
             + a1.x*a1.x + a1.y*a1.y + a1.z*a1.z + a1.w*a1.w
             + a2.x*a2.x + a2.y*a2.y + a2.z*a2.z + a2.w*a2.w
             + a3.x*a3.x + a3.y*a3.y + a3.z*a3.z + a3.w*a3.w;
        stt += b0.x*b0.x + b0.y*b0.y + b0.z*b0.z + b0.w*b0.w
             + b1.x*b1.x + b1.y*b1.y + b1.z*b1.z + b1.w*b1.w
             + b2.x*b2.x + b2.y*b2.y + b2.z*b2.z + b2.w*b2.w
             + b3.x*b3.x + b3.y*b3.y + b3.z*b3.z + b3.w*b3.w;
        spt += a0.x*b0.x + a0.y*b0.y + a0.z*b0.z + a0.w*b0.w
             + a1.x*b1.x + a1.y*b1.y + a1.z*b1.z + a1.w*b1.w
             + a2.x*b2.x + a2.y*b2.y + a2.z*b2.z + a2.w*b2.w
             + a3.x*b3.x + a3.y*b3.y + a3.z*b3.z + a3.w*b3.w;
    }

    // Wave (64-lane) shuffle reduction.
    #pragma unroll
    for (int off = 32; off > 0; off >>= 1) {
        sp  += __shfl_down(sp,  off);
        st  += __shfl_down(st,  off);
        spp += __shfl_down(spp, off);
        stt += __shfl_down(stt, off);
        spt += __shfl_down(spt, off);
    }

    __shared__ float ws[8][5];
    const int lane = tid & 63;
    const int wave = tid >> 6;
    if (lane == 0) {
        ws[wave][0] = sp;  ws[wave][1] = st;  ws[wave][2] = spp;
        ws[wave][3] = stt; ws[wave][4] = spt;
    }
    __syncthreads();

    if (tid == 0) {
        float S_p = 0.f, S_t = 0.f, S_pp = 0.f, S_tt = 0.f, S_pt = 0.f;
        #pragma unroll
        for (int w = 0; w < 8; ++w) {
            S_p  += ws[w][0]; S_t  += ws[w][1]; S_pp += ws[w][2];
            S_tt += ws[w][3]; S_pt += ws[w][4];
        }

        const float T   = (float)T_LEN;
        const float inv = 1.0f / T;
        float cp2 = S_pp - S_p * S_p * inv;
        float ct2 = S_tt - S_t * S_t * inv;
        float num = S_pt - S_p * S_t * inv;

        float var_p = cp2 / (T - 1.0f);
        float var_t = ct2 / (T - 1.0f);
        float denom = sqrtf(cp2 * ct2);
        float safe  = (denom > 0.0f) ? denom : 1.0f;
        float corr  = num / safe;
        bool valid = (var_p > VAR_EPS) && (var_t > VAR_EPS) &&
                     (denom > 0.0f) && !isnan(corr);
        float loss = valid ? (1.0f - corr) : 1.0f;
        atomicAdd(out, loss * inv_B);
    }
}

extern "C" void kernel_launch(void* const* d_in, const int* in_sizes, int n_in,
                              void* d_out, int out_size, void* d_ws, size_t ws_size,
                              hipStream_t stream) {
    const float* pred   = (const float*)d_in[0];
    const float* target = (const float*)d_in[1];
    float* out = (float*)d_out;

    const int B = in_sizes[0] / T_LEN;

    // d_out is poisoned 0xAA before every timed launch -> zero it (capture-safe).
    hipMemsetAsync(out, 0, sizeof(float), stream);
    pearson_row_kernel<<<B, 512, 0, stream>>>(pred, target, out, 1.0f / (float)B);
}